// Round 4
// baseline (260.607 us; speedup 1.0000x reference)
//
#include <hip/hip_runtime.h>

// Dense 2D spatial transformer (bilinear warp, dense flow), 4096x4096 f32.
//
// Round 8: tile pipelining. R7 post-mortem: interior math specialization cut
// VALUBusy 34->22% yet dur went 62.8->78us with OccupancyPercent 72->30%.
// Diagnosis: one tile per block => the staging chain (issue loads -> vmcnt(0)
// -> ds_write -> barrier) is fully EXPOSED; blocks sit stalled at the barrier
// (hence 30% achieved occupancy), and R7 also pushed flow loads ahead of
// staging loads, lengthening that pre-barrier critical path.
//
// Fix: each block processes KT=4 stacked 16x128 tiles with double-buffered
// LDS. Steady state per tile: issue stage(t+1) + flow(t+1), THEN compute(t),
// then barrier -- the next tile's load latency hides under this tile's
// compute, so the barrier's implicit vmcnt(0)/lgkmcnt(0) drain is no longer
// exposed. Staging for interior tiles needs zero clamps (window provably
// in-image). Border handled per-tile (ty 0/255) and per-block (bx 0/31) via
// the full-exact path -- identical pixel partition and identical expression
// trees to the passing R7, so output is unchanged.
//
// Reference math (full path, verbatim from passing R5/R6/R7):
//   H_up=(flow_h+h)+1 ; W_up=(flow_w+w)+1 ; hf=floor, hc=hf+1, clamp to
//   [0,H+1] (padded dims); dH=(float)hc_clamped-H_up (clamp BEFORE weights);
//   out = v00*(dW*dH)+v01*((1-dW)*dH)+v10*(dW*(1-dH))+v11*((1-dW)*(1-dH));
//   out-of-image taps contribute 0 via zeroed weights; row taps paired as
//   float2 from base cb=clamp(cf,0,W-2) with {0,1} selectors folded into the
//   weights. Interior fast path == this expression with clamps inactive.

#define IMG_H 4096
#define IMG_W 4096
#define TR 16                 // output rows per tile
#define TC 128                // output cols per tile/block
#define HALO 8
#define SR (TR + 2 * HALO)    // 32 staged rows
#define SC (TC + 2 * HALO)    // 144 staged cols
#define SC4 (SC / 4)          // 36 float4 per staged row
#define NCHUNK (SR * SC4)     // 1152 float4 stage chunks
#define KT 4                  // tiles per block (vertical)
#define BTR (TR * KT)         // 64 rows per block
#define NTY (IMG_H / TR)      // 256 tile-rows globally

typedef float f2  __attribute__((ext_vector_type(2)));              // 8B-aligned
typedef float f2u __attribute__((ext_vector_type(2), aligned(4)));  // 4B-aligned pair
typedef float f4  __attribute__((ext_vector_type(4)));

// Full-exact per-pixel path (reference math + global paired gathers).
__device__ __forceinline__ float full_pixel(const float* __restrict__ img,
                                            float fhv, float fwv, int h, int w)
{
    float Hu = (fhv + (float)h) + 1.0f;   // exact reference grouping
    float Wu = (fwv + (float)w) + 1.0f;

    int hf = (int)floorf(Hu);
    int wf = (int)floorf(Wu);
    int hc = hf + 1;
    int wc = wf + 1;

    int hfc = min(max(hf, 0), IMG_H + 1);
    int hcc = min(max(hc, 0), IMG_H + 1);
    int wfc = min(max(wf, 0), IMG_W + 1);
    int wcc = min(max(wc, 0), IMG_W + 1);

    float dH = (float)hcc - Hu;
    float dW = (float)wcc - Wu;

    int rf = hfc - 1, rc = hcc - 1, cf = wfc - 1, cc = wcc - 1;
    bool rf_in = (unsigned)rf < IMG_H;
    bool rc_in = (unsigned)rc < IMG_H;
    bool cf_in = (unsigned)cf < IMG_W;
    bool cc_in = (unsigned)cc < IMG_W;

    int rf_cl = min(max(rf, 0), IMG_H - 1);
    int rc_cl = min(max(rc, 0), IMG_H - 1);
    int cf_cl = min(max(cf, 0), IMG_W - 1);
    int cc_cl = min(max(cc, 0), IMG_W - 1);
    int cb    = min(max(cf, 0), IMG_W - 2);   // float2 pair base

    int sf = cf_cl - cb;   // 0 or 1
    int sc = cc_cl - cb;   // 0 or 1

    float A = dW * dH;
    float B = dW * (1.0f - dH);
    float C = (1.0f - dW) * dH;
    float D = (1.0f - dW) * (1.0f - dH);
    float w00 = (rf_in && cf_in) ? A : 0.0f;
    float w10 = (rc_in && cf_in) ? B : 0.0f;
    float w01 = (rf_in && cc_in) ? C : 0.0f;
    float w11 = (rc_in && cc_in) ? D : 0.0f;

    float a0x = (sf ? 0.0f : w00) + (sc ? 0.0f : w01);
    float a0y = (sf ? w00 : 0.0f) + (sc ? w01 : 0.0f);
    float a1x = (sf ? 0.0f : w10) + (sc ? 0.0f : w11);
    float a1y = (sf ? w10 : 0.0f) + (sc ? w11 : 0.0f);

    f2u p0 = *(const f2u*)(img + (rf_cl << 12) + cb);
    f2u p1 = *(const f2u*)(img + (rc_cl << 12) + cb);
    return p0.x * a0x + p0.y * a0y + p1.x * a1x + p1.y * a1y;
}

__global__ __launch_bounds__(256) void warp_bilinear_kernel(
    const float* __restrict__ img,   // [H, W]
    const float* __restrict__ flow,  // [2, H, W]
    float* __restrict__ out)         // [H, W]
{
    __shared__ float tile[2][SR * SC];   // 2 x 18432 B

    const int HW   = IMG_H * IMG_W;
    const int tid  = threadIdx.x;
    const int lane = tid & 63;
    const int wv   = tid >> 6;                      // 0..3
    const int bx   = blockIdx.x, by = blockIdx.y;
    const int w0   = bx * TC + lane * 2;            // 2 cols/thread (even)
    const int c_lo = bx * TC - HALO;

    // ---- x-border blocks: full-exact path, no LDS, no barriers ----
    if (bx == 0 || bx == (int)gridDim.x - 1) {
        #pragma unroll
        for (int t = 0; t < KT; ++t) {
            const int h0 = by * BTR + t * TR + wv * 4;
            int rowidx[4]; f2 fh[4], fw[4];
            #pragma unroll
            for (int r = 0; r < 4; ++r)
                rowidx[r] = (h0 + r) * IMG_W + w0;
            #pragma unroll
            for (int r = 0; r < 4; ++r)
                fh[r] = __builtin_nontemporal_load((const f2*)(flow + rowidx[r]));
            #pragma unroll
            for (int r = 0; r < 4; ++r)
                fw[r] = __builtin_nontemporal_load((const f2*)(flow + HW + rowidx[r]));
            #pragma unroll
            for (int r = 0; r < 4; ++r) {
                f2 res;
                #pragma unroll
                for (int c = 0; c < 2; ++c)
                    res[c] = full_pixel(img, fh[r][c], fw[r][c], h0 + r, w0 + c);
                __builtin_nontemporal_store(res, (f2*)(out + rowidx[r]));
            }
        }
        return;
    }

    // staging thread mapping (constant across tiles)
    int  sg_i[5], sg_m[5];
    bool sg_on[5];
    #pragma unroll
    for (int it = 0; it < 5; ++it) {
        int t = tid + it * 256;
        sg_on[it] = (t < NCHUNK);
        sg_i[it]  = t / SC4;
        sg_m[it]  = (t - sg_i[it] * SC4) * 4;
    }

    const int  ty0  = by * KT;
    const bool tb_f = (ty0 == 0);            // first tile is y-border
    const bool tb_l = (ty0 + KT - 1 == NTY - 1);  // last tile is y-border

    // interior-tile staging: window provably in-image, NO clamps
    auto stage = [&](int buf, int t) {
        const int r_lo = by * BTR + t * TR - HALO;
        #pragma unroll
        for (int it = 0; it < 5; ++it)
            if (sg_on[it]) {
                f4 v = *(const f4*)(img + (r_lo + sg_i[it]) * IMG_W
                                       + (c_lo + sg_m[it]));
                *(f4*)(&tile[buf][sg_i[it] * SC + sg_m[it]]) = v;
            }
    };

    f2  FH[2][4], FW[2][4];
    int RI[2][4];
    auto flowload = [&](int buf, int t) {
        const int h0 = by * BTR + t * TR + wv * 4;
        #pragma unroll
        for (int r = 0; r < 4; ++r)
            RI[buf][r] = (h0 + r) * IMG_W + w0;
        #pragma unroll
        for (int r = 0; r < 4; ++r)
            FH[buf][r] = __builtin_nontemporal_load((const f2*)(flow + RI[buf][r]));
        #pragma unroll
        for (int r = 0; r < 4; ++r)
            FW[buf][r] = __builtin_nontemporal_load((const f2*)(flow + HW + RI[buf][r]));
    };

    // ---- prologue: stage tile 0 (if interior), load its flow ----
    if (!tb_f) stage(0, 0);
    flowload(0, 0);
    __syncthreads();

    // ---- pipelined tile loop ----
    #pragma unroll
    for (int t = 0; t < KT; ++t) {
        const int cur = t & 1;

        // issue next tile's staging + flow loads BEFORE computing this tile
        if (t + 1 < KT) {
            const bool nb = (t + 1 == KT - 1) && tb_l;
            if (!nb) stage(cur ^ 1, t + 1);
            flowload(cur ^ 1, t + 1);
        }

        const bool thisb = (t == 0 && tb_f) || (t == KT - 1 && tb_l);
        const int  h0    = by * BTR + t * TR + wv * 4;

        if (thisb) {
            // y-border tile: full-exact path (LDS of this buf unused)
            #pragma unroll
            for (int r = 0; r < 4; ++r) {
                f2 res;
                #pragma unroll
                for (int c = 0; c < 2; ++c)
                    res[c] = full_pixel(img, FH[cur][r][c], FW[cur][r][c],
                                        h0 + r, w0 + c);
                __builtin_nontemporal_store(res, (f2*)(out + RI[cur][r]));
            }
        } else {
            // interior fast path: clamps provably inactive once in-window
            const int r_lo  = by * BTR + t * TR - HALO;
            const int rbase = -1 - r_lo;   // i0 = hf + rbase
            const int cbase = -1 - c_lo;   // jb = wf + cbase

            int   li0[4][2];
            float A_[4][2], B_[4][2], C_[4][2], D_[4][2];
            bool  ok = true;

            #pragma unroll
            for (int r = 0; r < 4; ++r) {
                #pragma unroll
                for (int c = 0; c < 2; ++c) {
                    float Hu = (FH[cur][r][c] + (float)(h0 + r)) + 1.0f;
                    float Wu = (FW[cur][r][c] + (float)(w0 + c)) + 1.0f;

                    int hf = (int)floorf(Hu);
                    int wf = (int)floorf(Wu);
                    float dH = (float)(hf + 1) - Hu;
                    float dW = (float)(wf + 1) - Wu;

                    int i0 = hf + rbase;           // window row of top tap
                    int jb = wf + cbase;           // window col of pair base
                    ok = ok && ((unsigned)i0 < SR - 1) && ((unsigned)jb < SC - 1);
                    li0[r][c] = i0 * SC + jb;

                    float omH = 1.0f - dH, omW = 1.0f - dW;
                    A_[r][c] = dW * dH;            // (rf,cf) = pair0.x
                    C_[r][c] = omW * dH;           // (rf,cc) = pair0.y
                    B_[r][c] = dW * omH;           // (rc,cf) = pair1.x
                    D_[r][c] = omW * omH;          // (rc,cc) = pair1.y
                }
            }

            float res[4][2];
            if (__builtin_expect(ok, 1)) {
                float q0x[4][2], q0y[4][2], q1x[4][2], q1y[4][2];
                #pragma unroll
                for (int r = 0; r < 4; ++r)
                    #pragma unroll
                    for (int c = 0; c < 2; ++c) {
                        q0x[r][c] = tile[cur][li0[r][c]];
                        q0y[r][c] = tile[cur][li0[r][c] + 1];
                        q1x[r][c] = tile[cur][li0[r][c] + SC];
                        q1y[r][c] = tile[cur][li0[r][c] + SC + 1];
                    }
                #pragma unroll
                for (int r = 0; r < 4; ++r)
                    #pragma unroll
                    for (int c = 0; c < 2; ++c)
                        res[r][c] = q0x[r][c] * A_[r][c] + q0y[r][c] * C_[r][c]
                                  + q1x[r][c] * B_[r][c] + q1y[r][c] * D_[r][c];
            }
            if (__builtin_expect(!ok, 0)) {
                // tap escaped staged window (P ~ 0): full-exact recompute
                #pragma unroll
                for (int r = 0; r < 4; ++r)
                    #pragma unroll
                    for (int c = 0; c < 2; ++c)
                        res[r][c] = full_pixel(img, FH[cur][r][c], FW[cur][r][c],
                                               h0 + r, w0 + c);
            }

            #pragma unroll
            for (int r = 0; r < 4; ++r) {
                f2 v; v[0] = res[r][0]; v[1] = res[r][1];
                __builtin_nontemporal_store(v, (f2*)(out + RI[cur][r]));
            }
        }

        if (t + 1 < KT) __syncthreads();
    }
}

extern "C" void kernel_launch(void* const* d_in, const int* in_sizes, int n_in,
                              void* d_out, int out_size, void* d_ws, size_t ws_size,
                              hipStream_t stream) {
    const float* img  = (const float*)d_in[0];   // [1,1,4096,4096]
    const float* flow = (const float*)d_in[1];   // [1,2,4096,4096]
    float* out = (float*)d_out;                  // [1,1,4096,4096]

    dim3 grid(IMG_W / TC, IMG_H / BTR);          // (32, 64)
    dim3 block(256);
    warp_bilinear_kernel<<<grid, block, 0, stream>>>(img, flow, out);
}

// Round 5
// 254.141 us; speedup vs baseline: 1.0254x; 1.0254x over previous
//
#include <hip/hip_runtime.h>

// Dense 2D spatial transformer (bilinear warp, dense flow), 4096x4096 f32.
//
// Round 9: T14-correct pipeline. R8 post-mortem (86us, occ 23.7%, VALU 18%):
// the stage() lambda fused load+ds_write, so the compiler emitted the vmcnt
// drain BEFORE compute(t) -- stage latency fully exposed each iteration
// (T14 anti-pattern). R7's flow-before-stage ordering had the same exposure
// via vmcnt(0). R8 also created 4x-slow x-border blocks (straggler tail).
//
// Fixes, keeping the double-buffered KT=4 pipeline:
//  1. stage_load(t+1) -> VGPRs issued FIRST (oldest outstanding VMEM), flow
//     loads second, compute(t) third, stage_write LAST before the barrier:
//     the counted vmcnt before the ds_writes retires for free under compute.
//  2. Uniform blocks: no special border blocks. All blocks stage with
//     clamped staging addresses; the per-pixel fast-path predicate `ok` now
//     requires window-hit AND strictly-in-image taps (hf in [1,H-1], wf in
//     [1,W-1]) -- under which the reference's pad-clamps are provably
//     inactive, all 4 taps are in-image, and pair selectors are (0,1), so
//     the fast path equals the reference expression exactly. Ring pixels
//     whose taps cross the edge (~2% of lanes in ring blocks only) fall
//     back per-lane to the verbatim full_pixel path.
//
// Reference math (full path, verbatim from passing R5-R8):
//   H_up=(flow_h+h)+1 ; W_up=(flow_w+w)+1 ; hf=floor, hc=hf+1, clamp to
//   [0,H+1] (padded dims); dH=(float)hc_clamped-H_up (clamp BEFORE weights);
//   out = v00*(dW*dH)+v01*((1-dW)*dH)+v10*(dW*(1-dH))+v11*((1-dW)*(1-dH));
//   out-of-image taps contribute 0 via zeroed weights; row taps paired as
//   float2 from base cb=clamp(cf,0,W-2) with {0,1} selectors in the weights.

#define IMG_H 4096
#define IMG_W 4096
#define TR 16                 // output rows per tile
#define TC 128                // output cols per tile/block
#define HALO 8
#define SR (TR + 2 * HALO)    // 32 staged rows
#define SC (TC + 2 * HALO)    // 144 staged cols
#define SC4 (SC / 4)          // 36 float4 per staged row
#define NCHUNK (SR * SC4)     // 1152 float4 stage chunks
#define KT 4                  // tiles per block (vertical)
#define BTR (TR * KT)         // 64 rows per block

typedef float f2  __attribute__((ext_vector_type(2)));              // 8B-aligned
typedef float f2u __attribute__((ext_vector_type(2), aligned(4)));  // 4B-aligned pair
typedef float f4  __attribute__((ext_vector_type(4)));

// Full-exact per-pixel path (reference math + global paired gathers).
__device__ __forceinline__ float full_pixel(const float* __restrict__ img,
                                            float fhv, float fwv, int h, int w)
{
    float Hu = (fhv + (float)h) + 1.0f;   // exact reference grouping
    float Wu = (fwv + (float)w) + 1.0f;

    int hf = (int)floorf(Hu);
    int wf = (int)floorf(Wu);
    int hc = hf + 1;
    int wc = wf + 1;

    int hfc = min(max(hf, 0), IMG_H + 1);
    int hcc = min(max(hc, 0), IMG_H + 1);
    int wfc = min(max(wf, 0), IMG_W + 1);
    int wcc = min(max(wc, 0), IMG_W + 1);

    float dH = (float)hcc - Hu;
    float dW = (float)wcc - Wu;

    int rf = hfc - 1, rc = hcc - 1, cf = wfc - 1, cc = wcc - 1;
    bool rf_in = (unsigned)rf < IMG_H;
    bool rc_in = (unsigned)rc < IMG_H;
    bool cf_in = (unsigned)cf < IMG_W;
    bool cc_in = (unsigned)cc < IMG_W;

    int rf_cl = min(max(rf, 0), IMG_H - 1);
    int rc_cl = min(max(rc, 0), IMG_H - 1);
    int cf_cl = min(max(cf, 0), IMG_W - 1);
    int cc_cl = min(max(cc, 0), IMG_W - 1);
    int cb    = min(max(cf, 0), IMG_W - 2);   // float2 pair base

    int sf = cf_cl - cb;   // 0 or 1
    int sc = cc_cl - cb;   // 0 or 1

    float A = dW * dH;
    float B = dW * (1.0f - dH);
    float C = (1.0f - dW) * dH;
    float D = (1.0f - dW) * (1.0f - dH);
    float w00 = (rf_in && cf_in) ? A : 0.0f;
    float w10 = (rc_in && cf_in) ? B : 0.0f;
    float w01 = (rf_in && cc_in) ? C : 0.0f;
    float w11 = (rc_in && cc_in) ? D : 0.0f;

    float a0x = (sf ? 0.0f : w00) + (sc ? 0.0f : w01);
    float a0y = (sf ? w00 : 0.0f) + (sc ? w01 : 0.0f);
    float a1x = (sf ? 0.0f : w10) + (sc ? 0.0f : w11);
    float a1y = (sf ? w10 : 0.0f) + (sc ? w11 : 0.0f);

    f2u p0 = *(const f2u*)(img + (rf_cl << 12) + cb);
    f2u p1 = *(const f2u*)(img + (rc_cl << 12) + cb);
    return p0.x * a0x + p0.y * a0y + p1.x * a1x + p1.y * a1y;
}

__global__ __launch_bounds__(256) void warp_bilinear_kernel(
    const float* __restrict__ img,   // [H, W]
    const float* __restrict__ flow,  // [2, H, W]
    float* __restrict__ out)         // [H, W]
{
    __shared__ float tile[2][SR * SC];   // 2 x 18432 B

    const int HW    = IMG_H * IMG_W;
    const int tid   = threadIdx.x;
    const int lane  = tid & 63;
    const int wv    = tid >> 6;                     // 0..3
    const int bx    = blockIdx.x, by = blockIdx.y;
    const int w0    = bx * TC + lane * 2;           // 2 cols/thread (even)
    const int c_lo  = bx * TC - HALO;               // window origin (col)
    const int cbase = -1 - c_lo;                    // jb = wf + cbase

    // staging thread mapping (constant across tiles); cols clamped in-image
    int  sg_i[5], sg_m[5], sg_c[5];
    bool sg_on[5];
    #pragma unroll
    for (int it = 0; it < 5; ++it) {
        int t = tid + it * 256;
        sg_on[it] = (t < NCHUNK);
        sg_i[it]  = t / SC4;
        sg_m[it]  = (t - sg_i[it] * SC4) * 4;
        sg_c[it]  = min(max(c_lo + sg_m[it], 0), IMG_W - 4);
    }

    f4  S[5];                 // in-flight staged chunks (write-late, T14)
    f2  FH[2][4], FW[2][4];
    int RI[2][4];

    // issue staging loads for tile t into S (rows clamped in-image)
    auto stage_load = [&](int t) {
        const int r_lo = by * BTR + t * TR - HALO;
        #pragma unroll
        for (int it = 0; it < 5; ++it)
            if (sg_on[it]) {
                int gr = min(max(r_lo + sg_i[it], 0), IMG_H - 1);
                S[it] = *(const f4*)(img + gr * IMG_W + sg_c[it]);
            }
    };
    // commit S to LDS buffer (placed AFTER compute so vmcnt retires free)
    auto stage_write = [&](int buf) {
        #pragma unroll
        for (int it = 0; it < 5; ++it)
            if (sg_on[it])
                *(f4*)(&tile[buf][sg_i[it] * SC + sg_m[it]]) = S[it];
    };
    auto flow_load = [&](int buf, int t) {
        const int h0 = by * BTR + t * TR + wv * 4;
        #pragma unroll
        for (int r = 0; r < 4; ++r)
            RI[buf][r] = (h0 + r) * IMG_W + w0;
        #pragma unroll
        for (int r = 0; r < 4; ++r)
            FH[buf][r] = __builtin_nontemporal_load((const f2*)(flow + RI[buf][r]));
        #pragma unroll
        for (int r = 0; r < 4; ++r)
            FW[buf][r] = __builtin_nontemporal_load((const f2*)(flow + HW + RI[buf][r]));
    };

    // ---- prologue: stage + flow for tile 0 (one exposed chain per block) ----
    stage_load(0);
    flow_load(0, 0);
    stage_write(0);
    __syncthreads();

    // ---- pipelined tile loop ----
    #pragma unroll
    for (int t = 0; t < KT; ++t) {
        const int cur = t & 1;

        // issue next tile's loads FIRST (stage loads = oldest outstanding)
        if (t + 1 < KT) {
            stage_load(t + 1);
            flow_load(cur ^ 1, t + 1);
        }

        // ---- compute tile t from tile[cur] ----
        const int h0    = by * BTR + t * TR + wv * 4;
        const int r_lo  = by * BTR + t * TR - HALO;
        const int rbase = -1 - r_lo;   // i0 = hf + rbase = rf - r_lo

        int   li0[4][2];
        float A_[4][2], B_[4][2], C_[4][2], D_[4][2];
        bool  ok = true;

        #pragma unroll
        for (int r = 0; r < 4; ++r) {
            #pragma unroll
            for (int c = 0; c < 2; ++c) {
                // exact reference grouping: (flow + mesh) + 1.0
                float Hu = (FH[cur][r][c] + (float)(h0 + r)) + 1.0f;
                float Wu = (FW[cur][r][c] + (float)(w0 + c)) + 1.0f;

                int hf = (int)floorf(Hu);
                int wf = (int)floorf(Wu);
                float dH = (float)(hf + 1) - Hu;
                float dW = (float)(wf + 1) - Wu;

                int i0 = hf + rbase;           // window row of top tap
                int jb = wf + cbase;           // window col of pair base

                // fast path valid iff taps strictly in-image (pad-clamps
                // provably inactive, selectors (0,1)) AND pair in window
                ok = ok && ((unsigned)(hf - 1) < IMG_H - 1)
                        && ((unsigned)(wf - 1) < IMG_W - 1)
                        && ((unsigned)i0 < SR - 1)
                        && ((unsigned)jb < SC - 1);
                li0[r][c] = i0 * SC + jb;

                float omH = 1.0f - dH, omW = 1.0f - dW;
                A_[r][c] = dW * dH;            // (rf,cf) = pair0.x
                C_[r][c] = omW * dH;           // (rf,cc) = pair0.y
                B_[r][c] = dW * omH;           // (rc,cf) = pair1.x
                D_[r][c] = omW * omH;          // (rc,cc) = pair1.y
            }
        }

        float res[4][2];
        if (__builtin_expect(ok, 1)) {
            float q0x[4][2], q0y[4][2], q1x[4][2], q1y[4][2];
            #pragma unroll
            for (int r = 0; r < 4; ++r)
                #pragma unroll
                for (int c = 0; c < 2; ++c) {
                    q0x[r][c] = tile[cur][li0[r][c]];
                    q0y[r][c] = tile[cur][li0[r][c] + 1];
                    q1x[r][c] = tile[cur][li0[r][c] + SC];
                    q1y[r][c] = tile[cur][li0[r][c] + SC + 1];
                }
            #pragma unroll
            for (int r = 0; r < 4; ++r)
                #pragma unroll
                for (int c = 0; c < 2; ++c)
                    res[r][c] = q0x[r][c] * A_[r][c] + q0y[r][c] * C_[r][c]
                              + q1x[r][c] * B_[r][c] + q1y[r][c] * D_[r][c];
        }
        if (__builtin_expect(!ok, 0)) {
            // ring pixel or escaped tap: full-exact recompute (rare)
            #pragma unroll
            for (int r = 0; r < 4; ++r)
                #pragma unroll
                for (int c = 0; c < 2; ++c)
                    res[r][c] = full_pixel(img, FH[cur][r][c], FW[cur][r][c],
                                           h0 + r, w0 + c);
        }

        #pragma unroll
        for (int r = 0; r < 4; ++r) {
            f2 v; v[0] = res[r][0]; v[1] = res[r][1];
            __builtin_nontemporal_store(v, (f2*)(out + RI[cur][r]));
        }

        // ---- write-late staging commit, then single barrier per tile ----
        if (t + 1 < KT) {
            stage_write(cur ^ 1);
            __syncthreads();
        }
    }
}

extern "C" void kernel_launch(void* const* d_in, const int* in_sizes, int n_in,
                              void* d_out, int out_size, void* d_ws, size_t ws_size,
                              hipStream_t stream) {
    const float* img  = (const float*)d_in[0];   // [1,1,4096,4096]
    const float* flow = (const float*)d_in[1];   // [1,2,4096,4096]
    float* out = (float*)d_out;                  // [1,1,4096,4096]

    dim3 grid(IMG_W / TC, IMG_H / BTR);          // (32, 64)
    dim3 block(256);
    warp_bilinear_kernel<<<grid, block, 0, stream>>>(img, flow, out);
}

// Round 6
// 239.108 us; speedup vs baseline: 1.0899x; 1.0629x over previous
//
#include <hip/hip_runtime.h>

// Dense 2D spatial transformer (bilinear warp, dense flow), 4096x4096 f32.
//
// Round 10: wave-autonomous LDS staging -- NO barriers. Era post-mortem:
// every __syncthreads-coupled variant (R6-R9: 62.8/78/86.5/79.4us) sits at
// occ 20-30% -- block-lockstep drains the stage round-trip nearly serially
// per tile. Barrier-free R5 (67us) ran at occ 72% and was limited only by
// divergent-gather TA service (~450 lines per 256px wave).
//
// Fix: each WAVE stages its own private 32x48 img window (halo 8) into its
// own LDS slab; ds_write -> (compiler lgkmcnt) -> ds_read2 gathers, no
// __syncthreads anywhere. Blocks are 4 independent waves; LDS 26KB/block ->
// 6 blocks/CU -> 24-wave (75%) occupancy cap, so TLP hides the staging
// latency exactly as it hid R5's gather latency. TA cost per 512-px wave
// drops ~450 -> ~206 lines (coalesced f4 staging + f2 flow/stores);
// gathers move to the parallel LDS pipe. Binding pipe becomes the 190MB
// HBM stream (~30us floor).
//
// Wave tile: 32 cols x 16 rows (512 px, 8 px/thread). lane = 16 col-pairs
// x 4 row-groups; px rows = rgrp + 4k. LDS row stride 52 dwords (16B-
// aligned rows for b128 writes; odd-row parity flip keeps ds_read2 pair
// gathers ~2-way). Window staging clamps addresses at image edges; those
// slots are never read by the fast path (its predicate requires taps
// strictly in-image AND in-window). Ring pixels / escaped taps (P~0,
// max|flow|~5.5 < HALO=8) fall back per-lane-group to full_pixel.
//
// Reference math (full path, verbatim from passing R5-R9):
//   H_up=(flow_h+h)+1 ; W_up=(flow_w+w)+1 ; hf=floor, hc=hf+1, clamp to
//   [0,H+1] (padded dims); dH=(float)hc_clamped-H_up (clamp BEFORE weights);
//   out = v00*(dW*dH)+v01*((1-dW)*dH)+v10*(dW*(1-dH))+v11*((1-dW)*(1-dH));
//   out-of-image taps contribute 0 via zeroed weights. Fast path == this
//   with clamps provably inactive (1<=hf<=4095, 1<=wf<=4095).

#define IMG_H 4096
#define IMG_W 4096
#define HALO 8
#define WTR 16                    // wave tile rows
#define WTC 32                    // wave tile cols
#define SRW (WTR + 2 * HALO)      // 32 staged rows
#define SCW (WTC + 2 * HALO)      // 48 staged cols
#define LSTRIDE 52                // dword row stride (16B-aligned rows)
#define SLAB (SRW * LSTRIDE)      // 1664 dwords = 6656 B per wave
#define NCPR (SCW / 4)            // 12 float4 chunks per staged row

typedef float f2  __attribute__((ext_vector_type(2)));              // 8B-aligned
typedef float f2u __attribute__((ext_vector_type(2), aligned(4)));  // 4B-aligned pair
typedef float f4  __attribute__((ext_vector_type(4)));

// Full-exact per-pixel path (reference math + global paired gathers).
__device__ __forceinline__ float full_pixel(const float* __restrict__ img,
                                            float fhv, float fwv, int h, int w)
{
    float Hu = (fhv + (float)h) + 1.0f;   // exact reference grouping
    float Wu = (fwv + (float)w) + 1.0f;

    int hf = (int)floorf(Hu);
    int wf = (int)floorf(Wu);
    int hc = hf + 1;
    int wc = wf + 1;

    int hfc = min(max(hf, 0), IMG_H + 1);
    int hcc = min(max(hc, 0), IMG_H + 1);
    int wfc = min(max(wf, 0), IMG_W + 1);
    int wcc = min(max(wc, 0), IMG_W + 1);

    float dH = (float)hcc - Hu;
    float dW = (float)wcc - Wu;

    int rf = hfc - 1, rc = hcc - 1, cf = wfc - 1, cc = wcc - 1;
    bool rf_in = (unsigned)rf < IMG_H;
    bool rc_in = (unsigned)rc < IMG_H;
    bool cf_in = (unsigned)cf < IMG_W;
    bool cc_in = (unsigned)cc < IMG_W;

    int rf_cl = min(max(rf, 0), IMG_H - 1);
    int rc_cl = min(max(rc, 0), IMG_H - 1);
    int cf_cl = min(max(cf, 0), IMG_W - 1);
    int cc_cl = min(max(cc, 0), IMG_W - 1);
    int cb    = min(max(cf, 0), IMG_W - 2);   // float2 pair base

    int sf = cf_cl - cb;   // 0 or 1
    int sc = cc_cl - cb;   // 0 or 1

    float A = dW * dH;
    float B = dW * (1.0f - dH);
    float C = (1.0f - dW) * dH;
    float D = (1.0f - dW) * (1.0f - dH);
    float w00 = (rf_in && cf_in) ? A : 0.0f;
    float w10 = (rc_in && cf_in) ? B : 0.0f;
    float w01 = (rf_in && cc_in) ? C : 0.0f;
    float w11 = (rc_in && cc_in) ? D : 0.0f;

    float a0x = (sf ? 0.0f : w00) + (sc ? 0.0f : w01);
    float a0y = (sf ? w00 : 0.0f) + (sc ? w01 : 0.0f);
    float a1x = (sf ? 0.0f : w10) + (sc ? 0.0f : w11);
    float a1y = (sf ? w10 : 0.0f) + (sc ? w11 : 0.0f);

    f2u p0 = *(const f2u*)(img + (rf_cl << 12) + cb);
    f2u p1 = *(const f2u*)(img + (rc_cl << 12) + cb);
    return p0.x * a0x + p0.y * a0y + p1.x * a1x + p1.y * a1y;
}

__global__ __launch_bounds__(256, 6) void warp_bilinear_kernel(
    const float* __restrict__ img,   // [H, W]
    const float* __restrict__ flow,  // [2, H, W]
    float* __restrict__ out)         // [H, W]
{
    __shared__ float lds[4 * SLAB];  // 26624 B; one private slab per wave

    const int HW    = IMG_H * IMG_W;
    const int tid   = threadIdx.x;
    const int lane  = tid & 63;
    const int wid   = tid >> 6;                          // wave 0..3
    const int cpair = lane & 15;                         // col-pair in tile
    const int rgrp  = lane >> 4;                         // 0..3
    const int bx    = blockIdx.x, by = blockIdx.y;

    float* slab = lds + wid * SLAB;

    const int c0    = bx * 128 + wid * WTC + cpair * 2;  // thread col (even)
    const int wr_lo = by * WTR - HALO;                   // window origin row
    const int wc_lo = bx * 128 + wid * WTC - HALO;       // window origin col
    const int rbase = -1 - wr_lo;                        // i0 = hf + rbase
    const int cbase = -1 - wc_lo;                        // jb = wf + cbase

    // ---- 1. issue private-window staging loads (6 coalesced float4) ----
    f4 S[6];
    #pragma unroll
    for (int j = 0; j < 6; ++j) {
        int ch  = lane + 64 * j;                         // 0..383
        int row = ch / NCPR;
        int m   = ch - row * NCPR;
        int gr  = min(max(wr_lo + row, 0), IMG_H - 1);   // edge-clamped;
        int gc  = min(max(wc_lo + 4 * m, 0), IMG_W - 4); // never read by fast path
        S[j] = *(const f4*)(img + gr * IMG_W + gc);
    }

    // ---- 2. flow loads (8 float2, streaming) ----
    int RI[4]; f2 FH[4], FW[4];
    #pragma unroll
    for (int k = 0; k < 4; ++k)
        RI[k] = (by * WTR + rgrp + 4 * k) * IMG_W + c0;
    #pragma unroll
    for (int k = 0; k < 4; ++k)
        FH[k] = __builtin_nontemporal_load((const f2*)(flow + RI[k]));
    #pragma unroll
    for (int k = 0; k < 4; ++k)
        FW[k] = __builtin_nontemporal_load((const f2*)(flow + HW + RI[k]));

    // ---- 3. commit window to this wave's slab (no barrier: wave-private;
    //         compiler orders via vmcnt before writes, lgkmcnt before reads)
    #pragma unroll
    for (int j = 0; j < 6; ++j) {
        int ch  = lane + 64 * j;
        int row = ch / NCPR;
        int m   = ch - row * NCPR;
        *(f4*)(slab + row * LSTRIDE + 4 * m) = S[j];
    }

    // ---- 4. two groups of 4 px: math -> LDS pair-gathers -> blend -> store
    #pragma unroll
    for (int g = 0; g < 2; ++g) {
        int   li[2][2];
        float A_[2][2], B_[2][2], C_[2][2], D_[2][2];
        bool  ok = true;

        #pragma unroll
        for (int kk = 0; kk < 2; ++kk) {
            const int k = 2 * g + kk;
            const int h = by * WTR + rgrp + 4 * k;
            #pragma unroll
            for (int c = 0; c < 2; ++c) {
                // exact reference grouping: (flow + mesh) + 1.0
                float Hu = (FH[k][c] + (float)h) + 1.0f;
                float Wu = (FW[k][c] + (float)(c0 + c)) + 1.0f;

                int hf = (int)floorf(Hu);
                int wf = (int)floorf(Wu);
                float dH = (float)(hf + 1) - Hu;
                float dW = (float)(wf + 1) - Wu;

                int i0 = hf + rbase;           // window row of top tap
                int jb = wf + cbase;           // window col of pair base

                // fast path valid iff taps strictly in-image (pad-clamps
                // provably inactive, selectors (0,1)) AND pair in window
                ok = ok && ((unsigned)(hf - 1) < IMG_H - 1)
                        && ((unsigned)(wf - 1) < IMG_W - 1)
                        && ((unsigned)i0 < SRW - 1)
                        && ((unsigned)jb < SCW - 1);
                li[kk][c] = i0 * LSTRIDE + jb;

                float omH = 1.0f - dH, omW = 1.0f - dW;
                A_[kk][c] = dW * dH;           // (rf,cf) = pair0.x
                C_[kk][c] = omW * dH;          // (rf,cc) = pair0.y
                B_[kk][c] = dW * omH;          // (rc,cf) = pair1.x
                D_[kk][c] = omW * omH;         // (rc,cc) = pair1.y
            }
        }

        float res[2][2];
        if (__builtin_expect(ok, 1)) {
            float q0x[2][2], q0y[2][2], q1x[2][2], q1y[2][2];
            #pragma unroll
            for (int kk = 0; kk < 2; ++kk)
                #pragma unroll
                for (int c = 0; c < 2; ++c) {
                    q0x[kk][c] = slab[li[kk][c]];
                    q0y[kk][c] = slab[li[kk][c] + 1];
                    q1x[kk][c] = slab[li[kk][c] + LSTRIDE];
                    q1y[kk][c] = slab[li[kk][c] + LSTRIDE + 1];
                }
            #pragma unroll
            for (int kk = 0; kk < 2; ++kk)
                #pragma unroll
                for (int c = 0; c < 2; ++c)
                    res[kk][c] = q0x[kk][c] * A_[kk][c] + q0y[kk][c] * C_[kk][c]
                               + q1x[kk][c] * B_[kk][c] + q1y[kk][c] * D_[kk][c];
        }
        if (__builtin_expect(!ok, 0)) {
            // ring pixel or escaped tap (P ~ 0): full-exact recompute
            #pragma unroll
            for (int kk = 0; kk < 2; ++kk) {
                const int k = 2 * g + kk;
                const int h = by * WTR + rgrp + 4 * k;
                #pragma unroll
                for (int c = 0; c < 2; ++c)
                    res[kk][c] = full_pixel(img, FH[k][c], FW[k][c],
                                            h, c0 + c);
            }
        }

        #pragma unroll
        for (int kk = 0; kk < 2; ++kk) {
            f2 v; v[0] = res[kk][0]; v[1] = res[kk][1];
            __builtin_nontemporal_store(v, (f2*)(out + RI[2 * g + kk]));
        }
    }
}

extern "C" void kernel_launch(void* const* d_in, const int* in_sizes, int n_in,
                              void* d_out, int out_size, void* d_ws, size_t ws_size,
                              hipStream_t stream) {
    const float* img  = (const float*)d_in[0];   // [1,1,4096,4096]
    const float* flow = (const float*)d_in[1];   // [1,2,4096,4096]
    float* out = (float*)d_out;                  // [1,1,4096,4096]

    dim3 grid(IMG_W / 128, IMG_H / WTR);         // (32, 256)
    dim3 block(256);
    warp_bilinear_kernel<<<grid, block, 0, stream>>>(img, flow, out);
}